// Round 3
// baseline (97.385 us; speedup 1.0000x reference)
//
#include <hip/hip_runtime.h>
#include <hip/hip_bf16.h>

typedef short s4 __attribute__((ext_vector_type(4)));
typedef short s8 __attribute__((ext_vector_type(8)));
typedef float f4 __attribute__((ext_vector_type(4)));

#define MFMA16(a, b, c) __builtin_amdgcn_mfma_f32_16x16x16bf16_1k(a, b, c, 0, 0, 0)

__device__ __forceinline__ short f2bf(float f) {
    union { float f; unsigned u; } v; v.f = f;
    unsigned r = v.u + 0x7fffu + ((v.u >> 16) & 1u);   // RNE
    return (short)(r >> 16);
}

// ---------------------------------------------------------------------------
// Kernel 0: pack W (f32 [1024][64]) -> fragment-ordered bf16.
// Layout: s8 index (ks*64 + ln)*2 + h ; s8 holds B-frags (nf=2h,e0..3),(nf=2h+1,e0..3)
// where frag elem e = W[k = 16*ks + 4*(ln>>4) + e][n = 16*nf + (ln&15)].
// grid (32, 3), block 256. 8192 s8 per matrix = 128 KB bf16 (L2-resident).
// ---------------------------------------------------------------------------
struct WcArgs { const float* W[3]; unsigned short* Wf; };

__global__ __launch_bounds__(256) void wconv_kernel(WcArgs a) {
    const int which = blockIdx.y;
    const int id = blockIdx.x * 256 + threadIdx.x;      // 0..8191
    const int ks = id >> 7, ln = (id >> 1) & 63, h = id & 1;
    const int lg = ln >> 4, lr = ln & 15;
    const float* W = a.W[which];
    s8 o;
    #pragma unroll
    for (int i = 0; i < 8; ++i) {
        int nf = 2 * h + (i >> 2), e = i & 3;
        o[i] = f2bf(W[(ks * 16 + 4 * lg + e) * 64 + nf * 16 + lr]);
    }
    ((s8*)a.Wf)[(size_t)which * 8192 + id] = o;
}

// ---------------------------------------------------------------------------
// Kernel 1: projections, zero-barrier K-split streaming.
// BM=32 rows/block, 256 thr (4 waves). Wave w owns K-quarter [256w, 256w+256):
// X flows global->VGPR A-frags (2-deep pipeline), W-frags from packed bf16 (L2).
// Cross-wave K-reduction via 26 KB LDS at the end (one sync).
// grid (512, 3) = 1536 blocks.
// ---------------------------------------------------------------------------
struct ProjArgs {
    const float* X[3];
    const float* b[3];
    const unsigned short* Wf;
    unsigned short* O[3];
};

__global__ __launch_bounds__(256) void proj_kernel(ProjArgs args) {
    __shared__ float lred[3][32][68];

    const int t  = threadIdx.x;
    const int wv = t >> 6, ln = t & 63, lg = ln >> 4, lr = ln & 15;
    const int which = blockIdx.y;
    const int r0 = blockIdx.x * 32;

    const float* xbase = args.X[which] + (size_t)(r0 + lr) * 1024 + wv * 256 + 4 * lg;
    const s8*    wf    = (const s8*)args.Wf + (size_t)which * 8192 + (wv * 16) * 128 + ln * 2;

    f4 acc[2][4];
    #pragma unroll
    for (int rg = 0; rg < 2; ++rg)
        #pragma unroll
        for (int nf = 0; nf < 4; ++nf) acc[rg][nf] = f4{0, 0, 0, 0};

    f4 xq[4][2];   // 2-deep X prefetch (slots by j&3)
    s8 wq[2][2];   // 1-deep W prefetch (slots by j&1)

#define LX(n) { xq[(n) & 3][0] = *(const f4*)(xbase + (n) * 16);               \
                xq[(n) & 3][1] = *(const f4*)(xbase + 16 * 1024 + (n) * 16); }
#define LW(n) { wq[(n) & 1][0] = wf[(n) * 128];                                \
                wq[(n) & 1][1] = wf[(n) * 128 + 1]; }

    LX(0); LX(1); LW(0);

    #pragma unroll
    for (int j = 0; j < 16; ++j) {
        if (j + 2 < 16) LX(j + 2);
        if (j + 1 < 16) LW(j + 1);
        s8 wa = wq[j & 1][0], wb = wq[j & 1][1];
        s4 w0 = __builtin_shufflevector(wa, wa, 0, 1, 2, 3);
        s4 w1 = __builtin_shufflevector(wa, wa, 4, 5, 6, 7);
        s4 w2 = __builtin_shufflevector(wb, wb, 0, 1, 2, 3);
        s4 w3 = __builtin_shufflevector(wb, wb, 4, 5, 6, 7);
        #pragma unroll
        for (int rg = 0; rg < 2; ++rg) {
            f4 x = xq[j & 3][rg];
            s4 a;
            a[0] = f2bf(x[0]); a[1] = f2bf(x[1]);
            a[2] = f2bf(x[2]); a[3] = f2bf(x[3]);
            acc[rg][0] = MFMA16(a, w0, acc[rg][0]);
            acc[rg][1] = MFMA16(a, w1, acc[rg][1]);
            acc[rg][2] = MFMA16(a, w2, acc[rg][2]);
            acc[rg][3] = MFMA16(a, w3, acc[rg][3]);
        }
    }
#undef LX
#undef LW

    // ---- cross-wave K-reduction ----
    if (wv > 0) {
        #pragma unroll
        for (int rg = 0; rg < 2; ++rg)
            #pragma unroll
            for (int nf = 0; nf < 4; ++nf)
                #pragma unroll
                for (int e = 0; e < 4; ++e)
                    lred[wv - 1][16 * rg + 4 * lg + e][16 * nf + lr] = acc[rg][nf][e];
    }
    __syncthreads();
    if (wv == 0) {
        const float* bias = args.b[which];
        unsigned short* O = args.O[which] + (size_t)r0 * 64;
        #pragma unroll
        for (int nf = 0; nf < 4; ++nf) {
            float bs = bias[16 * nf + lr];
            #pragma unroll
            for (int rg = 0; rg < 2; ++rg)
                #pragma unroll
                for (int e = 0; e < 4; ++e) {
                    int row = 16 * rg + 4 * lg + e, col = 16 * nf + lr;
                    float s = acc[rg][nf][e] + lred[0][row][col] + lred[1][row][col]
                            + lred[2][row][col] + bs;
                    O[(size_t)row * 64 + col] = (unsigned short)f2bf(s);
                }
        }
    }
}

// ---------------------------------------------------------------------------
// Kernel 2: causal flash attention (unchanged — ~7 us).
// ---------------------------------------------------------------------------
__global__ __launch_bounds__(256) void attn_kernel(const unsigned short* __restrict__ qp,
                                                   const unsigned short* __restrict__ kp,
                                                   const unsigned short* __restrict__ vp,
                                                   float* __restrict__ out) {
    __shared__ short lK[64][72];   // [key][d]
    __shared__ short lV[64][76];   // [d][key] (transposed)

    const int t  = threadIdx.x;
    const int wv = t >> 6, ln = t & 63, lg = ln >> 4, lr = ln & 15;
    const int b  = blockIdx.y, qt = blockIdx.x;
    const int q0 = qt * 64;
    const int qrow = q0 + wv * 16 + lr;

    const unsigned short* qpb = qp + (size_t)b * 2048 * 64;

    s4 qf[4];
    #pragma unroll
    for (int ks = 0; ks < 4; ++ks)
        qf[ks] = *(const s4*)(qpb + (size_t)qrow * 64 + ks * 16 + 4 * lg);

    f4 accO[4] = {f4{0,0,0,0}, f4{0,0,0,0}, f4{0,0,0,0}, f4{0,0,0,0}};
    float m = -3e38f, lsum = 0.f;

    for (int kt = 0; kt <= qt; ++kt) {
        const unsigned short* kpb = kp + ((size_t)b * 2048 + kt * 64) * 64;
        const unsigned short* vpb = vp + ((size_t)b * 2048 + kt * 64) * 64;

        #pragma unroll
        for (int i = 0; i < 2; ++i) {
            int f = t + i * 256;
            int r = f >> 3, c8 = f & 7;
            s8 k8 = *(const s8*)(kpb + (size_t)r * 64 + c8 * 8);
            *(s8*)&lK[r][c8 * 8] = k8;
            s8 v8 = *(const s8*)(vpb + (size_t)r * 64 + c8 * 8);
            #pragma unroll
            for (int j = 0; j < 8; ++j) lV[c8 * 8 + j][r] = v8[j];
        }
        __syncthreads();

        f4 st[4];
        #pragma unroll
        for (int kf = 0; kf < 4; ++kf) {
            f4 a = f4{0,0,0,0};
            #pragma unroll
            for (int ks = 0; ks < 4; ++ks) {
                s4 kfr = *(const s4*)&lK[kf * 16 + lr][ks * 16 + 4 * lg];
                a = MFMA16(kfr, qf[ks], a);
            }
            st[kf] = a;
        }

        const bool diag = (kt == qt);
        const int kbase = kt * 64;
        float smax = -3e38f;
        #pragma unroll
        for (int kf = 0; kf < 4; ++kf) {
            #pragma unroll
            for (int e = 0; e < 4; ++e) {
                float s = st[kf][e] * 0.125f;
                if (diag && (kbase + kf * 16 + 4 * lg + e > qrow)) s = -3e38f;
                st[kf][e] = s;
                smax = fmaxf(smax, s);
            }
        }
        smax = fmaxf(smax, __shfl_xor(smax, 16));
        smax = fmaxf(smax, __shfl_xor(smax, 32));

        float mnew  = fmaxf(m, smax);
        float scale = __expf(m - mnew);
        float psum  = 0.f;
        s4 pf[4];
        #pragma unroll
        for (int kf = 0; kf < 4; ++kf) {
            f4 p;
            #pragma unroll
            for (int e = 0; e < 4; ++e) { p[e] = __expf(st[kf][e] - mnew); psum += p[e]; }
            s4 pb; pb[0]=f2bf(p[0]); pb[1]=f2bf(p[1]); pb[2]=f2bf(p[2]); pb[3]=f2bf(p[3]);
            pf[kf] = pb;
        }
        psum += __shfl_xor(psum, 16);
        psum += __shfl_xor(psum, 32);
        lsum = lsum * scale + psum;
        m = mnew;
        #pragma unroll
        for (int df = 0; df < 4; ++df) accO[df] *= scale;

        #pragma unroll
        for (int df = 0; df < 4; ++df) {
            #pragma unroll
            for (int kf = 0; kf < 4; ++kf) {
                s4 vf = *(const s4*)&lV[df * 16 + lr][kf * 16 + 4 * lg];
                accO[df] = MFMA16(vf, pf[kf], accO[df]);
            }
        }
        __syncthreads();
    }

    float inv = 1.f / lsum;
    float* ob = out + ((size_t)b * 2048 + qrow) * 64;
    #pragma unroll
    for (int df = 0; df < 4; ++df) {
        f4 o;
        #pragma unroll
        for (int e = 0; e < 4; ++e) o[e] = accO[df][e] * inv;
        *(f4*)(ob + df * 16 + 4 * lg) = o;
    }
}

// ---------------------------------------------------------------------------
extern "C" void kernel_launch(void* const* d_in, const int* in_sizes, int n_in,
                              void* d_out, int out_size, void* d_ws, size_t ws_size,
                              hipStream_t stream) {
    const float* q  = (const float*)d_in[0];
    const float* k  = (const float*)d_in[1];
    const float* v  = (const float*)d_in[2];
    // d_in[3] = causal mask (deterministic tril) — computed analytically
    const float* Wq = (const float*)d_in[4];
    const float* bq = (const float*)d_in[5];
    const float* Wk = (const float*)d_in[6];
    const float* bk = (const float*)d_in[7];
    const float* Wv = (const float*)d_in[8];
    const float* bv = (const float*)d_in[9];

    unsigned short* qp = (unsigned short*)d_ws;            // [16384][64] bf16
    unsigned short* kp = qp + (size_t)16384 * 64;
    unsigned short* vp = kp + (size_t)16384 * 64;
    unsigned short* Wf = vp + (size_t)16384 * 64;          // 3 x 128 KB packed W frags

    WcArgs wa;
    wa.W[0] = Wq; wa.W[1] = Wk; wa.W[2] = Wv;
    wa.Wf = Wf;
    wconv_kernel<<<dim3(32, 3), 256, 0, stream>>>(wa);

    ProjArgs pa;
    pa.X[0] = q;  pa.X[1] = k;  pa.X[2] = v;
    pa.b[0] = bq; pa.b[1] = bk; pa.b[2] = bv;
    pa.Wf = Wf;
    pa.O[0] = qp; pa.O[1] = kp; pa.O[2] = vp;
    proj_kernel<<<dim3(512, 3), 256, 0, stream>>>(pa);

    attn_kernel<<<dim3(32, 8), 256, 0, stream>>>(qp, kp, vp, (float*)d_out);
}